// Round 1
// baseline (145.335 us; speedup 1.0000x reference)
//
#include <hip/hip_runtime.h>

#define B_DIM   1024
#define IN_DIM  2048
#define OUT_DIM 4096

typedef __bf16 bf16x8 __attribute__((ext_vector_type(8)));
typedef float  f32x4  __attribute__((ext_vector_type(4)));
typedef unsigned short u16x8 __attribute__((ext_vector_type(8)));

// round-to-nearest-even fp32 -> bf16 bits
__device__ __forceinline__ unsigned short f2bf(float f) {
    union { float f; unsigned int u; } cv; cv.f = f;
    unsigned int u = cv.u;
    unsigned int r = 0x7fffu + ((u >> 16) & 1u);
    return (unsigned short)((u + r) >> 16);
}

// async global->LDS, 16B per lane. LDS dest is wave-uniform base + lane*16.
__device__ __forceinline__ void async16(const void* g, void* l) {
    __builtin_amdgcn_global_load_lds(
        (const __attribute__((address_space(1))) unsigned int*)g,
        (__attribute__((address_space(3))) unsigned int*)l,
        16, 0, 0);
}

// --------------------------------------------------------------------------
// Kernel 1: W [4096][2048] fp32  ->  protos bf16 [4096][2048] row-major,
//           protos[2c+r][d] = W[r*2048+d][c];  plus p_sq[o] = sum_d protos[o][d]^2 (fp32)
// grid (32 c-tiles, 32 d-tiles, 2 halves) x 256 threads
// --------------------------------------------------------------------------
extern "C" __global__ void transpose_psq(const float* __restrict__ W,
                                         unsigned short* __restrict__ protos,
                                         float* __restrict__ p_sq) {
    __shared__ float tile[64][65];   // +1 pad: conflict-free transposed read
    const int r  = blockIdx.z;
    const int c0 = blockIdx.x * 64;
    const int d0 = blockIdx.y * 64;
    const int t  = threadIdx.x;
    const int tc = t & 63;   // lane within wave
    const int tw = t >> 6;   // wave index 0..3

    // read phase: wave-coalesced rows of W
    const float* Wp = W + (size_t)(r * IN_DIM + d0 + tw) * IN_DIM + c0 + tc;
#pragma unroll
    for (int j = 0; j < 16; ++j)
        tile[tw + 4 * j][tc] = Wp[(size_t)(4 * j) * IN_DIM];
    __syncthreads();

    // write phase: coalesced along d; whole wave shares one output row o
#pragma unroll
    for (int j = 0; j < 16; ++j) {
        const int cl = tw + 4 * j;
        const float v = tile[tc][cl];
        const int o = 2 * (c0 + cl) + r;
        protos[(size_t)o * IN_DIM + d0 + tc] = f2bf(v);
        float s = v * v;
#pragma unroll
        for (int off = 32; off > 0; off >>= 1) s += __shfl_down(s, off);
        if (tc == 0) atomicAdd(p_sq + o, s);
    }
}

// --------------------------------------------------------------------------
// Kernel 2: x fp32 [1024][2048] -> xb bf16, x_sq[b] = ||x_b||^2 (fp32)
// grid 1024 x 256 threads, 8 elems/thread
// --------------------------------------------------------------------------
extern "C" __global__ void xcast_xsq(const float* __restrict__ x,
                                     unsigned short* __restrict__ xb,
                                     float* __restrict__ x_sq) {
    __shared__ float red[4];
    const int b = blockIdx.x;
    const int t = threadIdx.x;
    const float* xp = x + (size_t)b * IN_DIM + t * 8;
    const float4 v0 = ((const float4*)xp)[0];
    const float4 v1 = ((const float4*)xp)[1];
    u16x8 pk;
    pk[0] = f2bf(v0.x); pk[1] = f2bf(v0.y); pk[2] = f2bf(v0.z); pk[3] = f2bf(v0.w);
    pk[4] = f2bf(v1.x); pk[5] = f2bf(v1.y); pk[6] = f2bf(v1.z); pk[7] = f2bf(v1.w);
    *(u16x8*)(xb + (size_t)b * IN_DIM + t * 8) = pk;

    float s = v0.x * v0.x + v0.y * v0.y + v0.z * v0.z + v0.w * v0.w
            + v1.x * v1.x + v1.y * v1.y + v1.z * v1.z + v1.w * v1.w;
#pragma unroll
    for (int off = 32; off > 0; off >>= 1) s += __shfl_down(s, off);
    const int lane = t & 63, w = t >> 6;
    if (lane == 0) red[w] = s;
    __syncthreads();
    if (t == 0) x_sq[b] = red[0] + red[1] + red[2] + red[3];
}

// --------------------------------------------------------------------------
// Kernel 3: GEMM  out[b][o] = 2 * (A @ Bt^T)[b][o] - x_sq[b] - p_sq[o] - bias[o]
// A  = xb      bf16 [1024][2048] (M x K, K-contig)
// Bt = protos  bf16 [4096][2048] (N x K, K-contig)
// 128x128 tile, BK=32, 256 threads (4 waves 2x2, each 64x64 = 4x4 MFMA 16x16x32)
// grid (32 n-blocks, 8 m-blocks)
// --------------------------------------------------------------------------
extern "C" __global__ __launch_bounds__(256) void gemm_epi(
        const unsigned short* __restrict__ A,
        const unsigned short* __restrict__ Bt,
        const float* __restrict__ x_sq,
        const float* __restrict__ p_sq,
        const float* __restrict__ bias,
        float* __restrict__ out) {
    __shared__ __align__(16) unsigned short lA[128 * 32];  // 8 KB
    __shared__ __align__(16) unsigned short lB[128 * 32];  // 8 KB

    const int t  = threadIdx.x;
    const int m0 = blockIdx.y * 128;
    const int n0 = blockIdx.x * 128;

    // staging: each thread owns two 16B chunks of A-tile and two of B-tile
    const unsigned short* gA0 = A  + (size_t)(m0 + (t >> 2)) * IN_DIM + (t & 3) * 8;
    const unsigned short* gA1 = gA0 + (size_t)64 * IN_DIM;
    const unsigned short* gB0 = Bt + (size_t)(n0 + (t >> 2)) * IN_DIM + (t & 3) * 8;
    const unsigned short* gB1 = gB0 + (size_t)64 * IN_DIM;
    unsigned short* lA0 = lA + t * 8;
    unsigned short* lA1 = lA0 + 256 * 8;
    unsigned short* lB0 = lB + t * 8;
    unsigned short* lB1 = lB0 + 256 * 8;

    const int wave = t >> 6;
    const int lane = t & 63;
    const int wm = (wave & 1) * 64;
    const int wn = (wave >> 1) * 64;
    const int ln = lane & 15;
    const int qd = lane >> 4;

    f32x4 acc[4][4] = {};

    for (int k0 = 0; k0 < IN_DIM; k0 += 32) {
        async16(gA0, lA0); async16(gA1, lA1);
        async16(gB0, lB0); async16(gB1, lB1);
        gA0 += 32; gA1 += 32; gB0 += 32; gB1 += 32;
        __syncthreads();   // drains vmcnt(0): staged data visible

        bf16x8 af[4], bfr[4];
#pragma unroll
        for (int i = 0; i < 4; ++i) {
            af[i]  = *(const bf16x8*)(lA + (wm + i * 16 + ln) * 32 + qd * 8);
            bfr[i] = *(const bf16x8*)(lB + (wn + i * 16 + ln) * 32 + qd * 8);
        }
#pragma unroll
        for (int i = 0; i < 4; ++i)
#pragma unroll
            for (int j = 0; j < 4; ++j)
                acc[i][j] = __builtin_amdgcn_mfma_f32_16x16x32_bf16(
                                af[i], bfr[j], acc[i][j], 0, 0, 0);
        __syncthreads();   // all reads done before next stage overwrites
    }

    // epilogue: C/D layout col = lane&15, row = (lane>>4)*4 + reg
    const int rowb = m0 + wm;
    const int colb = n0 + wn;
#pragma unroll
    for (int j = 0; j < 4; ++j) {
        const int col = colb + j * 16 + ln;
        const float pb = p_sq[col] + bias[col];
#pragma unroll
        for (int i = 0; i < 4; ++i) {
            const int row0 = rowb + i * 16 + qd * 4;
#pragma unroll
            for (int rr = 0; rr < 4; ++rr) {
                const int row = row0 + rr;
                out[(size_t)row * OUT_DIM + col] = 2.0f * acc[i][j][rr] - x_sq[row] - pb;
            }
        }
    }
}

// --------------------------------------------------------------------------
extern "C" void kernel_launch(void* const* d_in, const int* in_sizes, int n_in,
                              void* d_out, int out_size, void* d_ws, size_t ws_size,
                              hipStream_t stream) {
    const float* x    = (const float*)d_in[0];   // [1024, 2048]
    const float* W    = (const float*)d_in[1];   // [4096, 2048]
    const float* bias = (const float*)d_in[2];   // [4096]
    float* out = (float*)d_out;

    char* ws = (char*)d_ws;
    unsigned short* protos = (unsigned short*)ws;                              // 16 MB
    unsigned short* xb     = (unsigned short*)(ws + (size_t)16 * 1024 * 1024); // 4 MB
    float* x_sq            = (float*)(ws + (size_t)20 * 1024 * 1024);          // 4 KB
    float* p_sq            = (float*)(ws + (size_t)20 * 1024 * 1024 + 8192);   // 16 KB

    hipMemsetAsync(p_sq, 0, OUT_DIM * sizeof(float), stream);
    transpose_psq<<<dim3(32, 32, 2), 256, 0, stream>>>(W, protos, p_sq);
    xcast_xsq<<<dim3(1024), 256, 0, stream>>>(x, xb, x_sq);
    gemm_epi<<<dim3(32, 8), 256, 0, stream>>>(xb, protos, x_sq, p_sq, bias, out);
}

// Round 2
// 137.424 us; speedup vs baseline: 1.0576x; 1.0576x over previous
//
#include <hip/hip_runtime.h>

#define B_DIM   1024
#define IN_DIM  2048
#define OUT_DIM 4096

typedef __bf16 bf16x8 __attribute__((ext_vector_type(8)));
typedef float  f32x4  __attribute__((ext_vector_type(4)));
typedef unsigned short u16x8 __attribute__((ext_vector_type(8)));

// round-to-nearest-even fp32 -> bf16 bits
__device__ __forceinline__ unsigned short f2bf(float f) {
    union { float f; unsigned int u; } cv; cv.f = f;
    unsigned int u = cv.u;
    unsigned int r = 0x7fffu + ((u >> 16) & 1u);
    return (unsigned short)((u + r) >> 16);
}

__device__ __forceinline__ float bf2f(unsigned short h) {
    union { unsigned int u; float f; } cv; cv.u = ((unsigned int)h) << 16;
    return cv.f;
}

// async global->LDS, 16B per lane. LDS dest must be wave-uniform base + lane*16.
__device__ __forceinline__ void async16(const void* g, void* l) {
    __builtin_amdgcn_global_load_lds(
        (const __attribute__((address_space(1))) unsigned int*)g,
        (__attribute__((address_space(3))) unsigned int*)l,
        16, 0, 0);
}

// --------------------------------------------------------------------------
// Kernel 1: W [4096][2048] fp32 -> protos bf16 [4096][2048],
//           protos[2c+r][d] = W[r*2048+d][c].  No reduction here (that was
//           the R0 bottleneck: 96 serial shuffles + 16 atomics per thread).
// grid (32 c-tiles, 32 d-tiles, 2 halves) x 256 threads
// --------------------------------------------------------------------------
extern "C" __global__ __launch_bounds__(256) void transpose_w(
        const float* __restrict__ W, unsigned short* __restrict__ protos) {
    __shared__ float tile[64][65];   // [d][c], +1 pad
    const int r  = blockIdx.z;
    const int c0 = blockIdx.x * 64;
    const int d0 = blockIdx.y * 64;
    const int t  = threadIdx.x;
    const int tc = t & 63;
    const int tw = t >> 6;

    // read: wave-coalesced rows of W (row = r*2048 + d, cols c0+lane)
    const float* Wp = W + (size_t)(r * IN_DIM + d0 + tw) * IN_DIM + c0 + tc;
#pragma unroll
    for (int j = 0; j < 16; ++j)
        tile[tw + 4 * j][tc] = Wp[(size_t)(4 * j) * IN_DIM];
    __syncthreads();

    // write: thread t -> c-row (t>>5)+8*pass, d-chunk (t&31)*2.
    // LDS bank = (2*chunk + j + crow) % 32 -> 2-way (free). Stores: 128B/row
    // contiguous per 32 lanes.
    const int chunk = t & 31;
#pragma unroll
    for (int pass = 0; pass < 8; ++pass) {
        const int cr = (t >> 5) + 8 * pass;
        const float v0 = tile[2 * chunk][cr];
        const float v1 = tile[2 * chunk + 1][cr];
        const int o = 2 * (c0 + cr) + r;
        ushort2 pk;
        pk.x = f2bf(v0); pk.y = f2bf(v1);
        *(ushort2*)(protos + (size_t)o * IN_DIM + d0 + 2 * chunk) = pk;
    }
}

// --------------------------------------------------------------------------
// Kernel 2: psb[o] = sum_d protos[o][d]^2 + bias[o]   (fp32 accumulate)
// one wave per output row; 1024 blocks x 256 threads
// --------------------------------------------------------------------------
extern "C" __global__ __launch_bounds__(256) void psq_bias(
        const unsigned short* __restrict__ protos,
        const float* __restrict__ bias,
        float* __restrict__ psb) {
    const int o    = blockIdx.x * 4 + (threadIdx.x >> 6);
    const int lane = threadIdx.x & 63;
    const unsigned short* p = protos + (size_t)o * IN_DIM + lane * 8;
    float s = 0.f;
#pragma unroll
    for (int it = 0; it < 4; ++it) {
        u16x8 v = *(const u16x8*)(p + it * 512);
#pragma unroll
        for (int e = 0; e < 8; ++e) {
            const float f = bf2f(v[e]);
            s += f * f;
        }
    }
#pragma unroll
    for (int off = 32; off > 0; off >>= 1) s += __shfl_down(s, off);
    if (lane == 0) psb[o] = s + bias[o];
}

// --------------------------------------------------------------------------
// Kernel 3: x fp32 [1024][2048] -> xb bf16, x_sq[b] = ||x_b||^2 (fp32 exact)
// --------------------------------------------------------------------------
extern "C" __global__ __launch_bounds__(256) void xcast_xsq(
        const float* __restrict__ x,
        unsigned short* __restrict__ xb,
        float* __restrict__ x_sq) {
    __shared__ float red[4];
    const int b = blockIdx.x;
    const int t = threadIdx.x;
    const float* xp = x + (size_t)b * IN_DIM + t * 8;
    const float4 v0 = ((const float4*)xp)[0];
    const float4 v1 = ((const float4*)xp)[1];
    u16x8 pk;
    pk[0] = f2bf(v0.x); pk[1] = f2bf(v0.y); pk[2] = f2bf(v0.z); pk[3] = f2bf(v0.w);
    pk[4] = f2bf(v1.x); pk[5] = f2bf(v1.y); pk[6] = f2bf(v1.z); pk[7] = f2bf(v1.w);
    *(u16x8*)(xb + (size_t)b * IN_DIM + t * 8) = pk;

    float s = v0.x * v0.x + v0.y * v0.y + v0.z * v0.z + v0.w * v0.w
            + v1.x * v1.x + v1.y * v1.y + v1.z * v1.z + v1.w * v1.w;
#pragma unroll
    for (int off = 32; off > 0; off >>= 1) s += __shfl_down(s, off);
    const int lane = t & 63, w = t >> 6;
    if (lane == 0) red[w] = s;
    __syncthreads();
    if (t == 0) x_sq[b] = red[0] + red[1] + red[2] + red[3];
}

// --------------------------------------------------------------------------
// Kernel 4: GEMM  out[b][o] = 2*(A @ Bt^T)[b][o] - x_sq[b] - psb[o]
// 128x128 tile, BK=32, 256 threads (4 waves 2x2, each 64x64 = 4x4 MFMA).
// Single-barrier double-buffered K-loop: prefetch next tile via async16
// BEFORE computing current tile, so global latency overlaps ds_read+MFMA
// (at 1 block/CU there are no other blocks to hide it for us).
// --------------------------------------------------------------------------
extern "C" __global__ __launch_bounds__(256) void gemm_epi(
        const unsigned short* __restrict__ A,
        const unsigned short* __restrict__ Bt,
        const float* __restrict__ x_sq,
        const float* __restrict__ psb,
        float* __restrict__ out) {
    __shared__ __align__(16) unsigned short lA[2][128 * 32];  // 2 x 8 KB
    __shared__ __align__(16) unsigned short lB[2][128 * 32];  // 2 x 8 KB

    const int t  = threadIdx.x;
    const int m0 = blockIdx.y * 128;
    const int n0 = blockIdx.x * 128;

    const unsigned short* gA0 = A  + (size_t)(m0 + (t >> 2)) * IN_DIM + (t & 3) * 8;
    const unsigned short* gA1 = gA0 + (size_t)64 * IN_DIM;
    const unsigned short* gB0 = Bt + (size_t)(n0 + (t >> 2)) * IN_DIM + (t & 3) * 8;
    const unsigned short* gB1 = gB0 + (size_t)64 * IN_DIM;

    const int wave = t >> 6;
    const int lane = t & 63;
    const int wm = (wave & 1) * 64;
    const int wn = (wave >> 1) * 64;
    const int ln = lane & 15;
    const int qd = lane >> 4;

    f32x4 acc[4][4] = {};

    // prologue: stage k-tile 0 into buffer 0
    async16(gA0, &lA[0][t * 8]); async16(gA1, &lA[0][t * 8 + 2048]);
    async16(gB0, &lB[0][t * 8]); async16(gB1, &lB[0][t * 8 + 2048]);
    gA0 += 32; gA1 += 32; gB0 += 32; gB1 += 32;

    int cur = 0;
#pragma unroll 2
    for (int it = 0; it < 64; ++it) {
        __syncthreads();          // buf[cur] staged (vmcnt drain) + prev reads done
        if (it < 63) {            // prefetch next tile into the other buffer
            const int nxt = cur ^ 1;
            async16(gA0, &lA[nxt][t * 8]); async16(gA1, &lA[nxt][t * 8 + 2048]);
            async16(gB0, &lB[nxt][t * 8]); async16(gB1, &lB[nxt][t * 8 + 2048]);
            gA0 += 32; gA1 += 32; gB0 += 32; gB1 += 32;
        }
        bf16x8 af[4], bfr[4];
#pragma unroll
        for (int i = 0; i < 4; ++i) {
            af[i]  = *(const bf16x8*)(&lA[cur][(wm + i * 16 + ln) * 32 + qd * 8]);
            bfr[i] = *(const bf16x8*)(&lB[cur][(wn + i * 16 + ln) * 32 + qd * 8]);
        }
#pragma unroll
        for (int i = 0; i < 4; ++i)
#pragma unroll
            for (int j = 0; j < 4; ++j)
                acc[i][j] = __builtin_amdgcn_mfma_f32_16x16x32_bf16(
                                af[i], bfr[j], acc[i][j], 0, 0, 0);
        cur ^= 1;
    }

    // epilogue: C/D layout col = lane&15, row = (lane>>4)*4 + reg
    const int rowb = m0 + wm;
    const int colb = n0 + wn;
#pragma unroll
    for (int j = 0; j < 4; ++j) {
        const int col = colb + j * 16 + ln;
        const float pb = psb[col];
#pragma unroll
        for (int i = 0; i < 4; ++i) {
            const int row0 = rowb + i * 16 + qd * 4;
#pragma unroll
            for (int rr = 0; rr < 4; ++rr) {
                const int row = row0 + rr;
                out[(size_t)row * OUT_DIM + col] = 2.0f * acc[i][j][rr] - x_sq[row] - pb;
            }
        }
    }
}

// --------------------------------------------------------------------------
extern "C" void kernel_launch(void* const* d_in, const int* in_sizes, int n_in,
                              void* d_out, int out_size, void* d_ws, size_t ws_size,
                              hipStream_t stream) {
    const float* x    = (const float*)d_in[0];   // [1024, 2048]
    const float* W    = (const float*)d_in[1];   // [4096, 2048]
    const float* bias = (const float*)d_in[2];   // [4096]
    float* out = (float*)d_out;

    char* ws = (char*)d_ws;
    unsigned short* protos = (unsigned short*)ws;                              // 16 MB
    unsigned short* xb     = (unsigned short*)(ws + (size_t)16 * 1024 * 1024); // 4 MB
    float* x_sq            = (float*)(ws + (size_t)20 * 1024 * 1024);          // 4 KB
    float* psb             = (float*)(ws + (size_t)20 * 1024 * 1024 + 8192);   // 16 KB

    transpose_w<<<dim3(32, 32, 2), 256, 0, stream>>>(W, protos);
    psq_bias<<<dim3(1024), 256, 0, stream>>>(protos, bias, psb);
    xcast_xsq<<<dim3(1024), 256, 0, stream>>>(x, xb, x_sq);
    gemm_epi<<<dim3(32, 8), 256, 0, stream>>>(xb, protos, x_sq, psb, out);
}

// Round 3
// 117.630 us; speedup vs baseline: 1.2355x; 1.1683x over previous
//
#include <hip/hip_runtime.h>

#define B_DIM   1024
#define IN_DIM  2048
#define OUT_DIM 4096

typedef __bf16 bf16x8 __attribute__((ext_vector_type(8)));
typedef float  f32x4  __attribute__((ext_vector_type(4)));
typedef unsigned short u16x8 __attribute__((ext_vector_type(8)));

// round-to-nearest-even fp32 -> bf16 bits
__device__ __forceinline__ unsigned short f2bf(float f) {
    union { float f; unsigned int u; } cv; cv.f = f;
    unsigned int u = cv.u;
    unsigned int r = 0x7fffu + ((u >> 16) & 1u);
    return (unsigned short)((u + r) >> 16);
}

__device__ __forceinline__ float bf2f(unsigned short h) {
    union { unsigned int u; float f; } cv; cv.u = ((unsigned int)h) << 16;
    return cv.f;
}

// async global->LDS, 16B per lane. LDS dest must be wave-uniform base + lane*16.
__device__ __forceinline__ void async16(const void* g, void* l) {
    __builtin_amdgcn_global_load_lds(
        (const __attribute__((address_space(1))) unsigned int*)g,
        (__attribute__((address_space(3))) unsigned int*)l,
        16, 0, 0);
}

// --------------------------------------------------------------------------
// Kernel 1: W [4096][2048] fp32 -> protos bf16 [4096][2048],
//           protos[2c+r][d] = W[r*2048+d][c].
// float4 reads (256B/row-pass), ushort4 writes (128B/row-pass).
// grid (32 c-tiles, 32 d-tiles, 2 halves) x 256 threads
// --------------------------------------------------------------------------
extern "C" __global__ __launch_bounds__(256) void transpose_w(
        const float* __restrict__ W, unsigned short* __restrict__ protos) {
    __shared__ float tile[64][65];   // [d][c], +1 pad
    const int r  = blockIdx.z;
    const int c0 = blockIdx.x * 64;
    const int d0 = blockIdx.y * 64;
    const int t  = threadIdx.x;
    const int g  = t >> 4;          // 0..15
    const int cc = (t & 15) * 4;    // col group, 4-float chunks

    // read: row d0+g+16p of W, cols c0+cc..+3 as float4
    const float* Wp = W + (size_t)(r * IN_DIM + d0 + g) * IN_DIM + c0 + cc;
#pragma unroll
    for (int p = 0; p < 4; ++p) {
        const float4 v = *(const float4*)(Wp + (size_t)(16 * p) * IN_DIM);
        const int dl = g + 16 * p;
        tile[dl][cc]     = v.x;
        tile[dl][cc + 1] = v.y;
        tile[dl][cc + 2] = v.z;
        tile[dl][cc + 3] = v.w;
    }
    __syncthreads();

    // write: c-row cr = g+16p, d-chunk cc..cc+3 -> protos row o, ushort4
#pragma unroll
    for (int p = 0; p < 4; ++p) {
        const int cr = g + 16 * p;
        const int o  = 2 * (c0 + cr) + r;
        ushort4 pk;
        pk.x = f2bf(tile[cc][cr]);
        pk.y = f2bf(tile[cc + 1][cr]);
        pk.z = f2bf(tile[cc + 2][cr]);
        pk.w = f2bf(tile[cc + 3][cr]);
        *(ushort4*)(protos + (size_t)o * IN_DIM + d0 + cc) = pk;
    }
}

// --------------------------------------------------------------------------
// Kernel 2: psb[o] = sum_d protos[o][d]^2 + bias[o]   (fp32 accumulate)
// --------------------------------------------------------------------------
extern "C" __global__ __launch_bounds__(256) void psq_bias(
        const unsigned short* __restrict__ protos,
        const float* __restrict__ bias,
        float* __restrict__ psb) {
    const int o    = blockIdx.x * 4 + (threadIdx.x >> 6);
    const int lane = threadIdx.x & 63;
    const unsigned short* p = protos + (size_t)o * IN_DIM + lane * 8;
    float s = 0.f;
#pragma unroll
    for (int it = 0; it < 4; ++it) {
        u16x8 v = *(const u16x8*)(p + it * 512);
#pragma unroll
        for (int e = 0; e < 8; ++e) {
            const float f = bf2f(v[e]);
            s += f * f;
        }
    }
#pragma unroll
    for (int off = 32; off > 0; off >>= 1) s += __shfl_down(s, off);
    if (lane == 0) psb[o] = s + bias[o];
}

// --------------------------------------------------------------------------
// Kernel 3: x fp32 [1024][2048] -> xb bf16, x_sq[b] = ||x_b||^2 (fp32 exact)
// --------------------------------------------------------------------------
extern "C" __global__ __launch_bounds__(256) void xcast_xsq(
        const float* __restrict__ x,
        unsigned short* __restrict__ xb,
        float* __restrict__ x_sq) {
    __shared__ float red[4];
    const int b = blockIdx.x;
    const int t = threadIdx.x;
    const float* xp = x + (size_t)b * IN_DIM + t * 8;
    const float4 v0 = ((const float4*)xp)[0];
    const float4 v1 = ((const float4*)xp)[1];
    u16x8 pk;
    pk[0] = f2bf(v0.x); pk[1] = f2bf(v0.y); pk[2] = f2bf(v0.z); pk[3] = f2bf(v0.w);
    pk[4] = f2bf(v1.x); pk[5] = f2bf(v1.y); pk[6] = f2bf(v1.z); pk[7] = f2bf(v1.w);
    *(u16x8*)(xb + (size_t)b * IN_DIM + t * 8) = pk;

    float s = v0.x * v0.x + v0.y * v0.y + v0.z * v0.z + v0.w * v0.w
            + v1.x * v1.x + v1.y * v1.y + v1.z * v1.z + v1.w * v1.w;
#pragma unroll
    for (int off = 32; off > 0; off >>= 1) s += __shfl_down(s, off);
    const int lane = t & 63, w = t >> 6;
    if (lane == 0) red[w] = s;
    __syncthreads();
    if (t == 0) x_sq[b] = red[0] + red[1] + red[2] + red[3];
}

// --------------------------------------------------------------------------
// Kernel 4: GEMM  out[b][o] = 2*(A @ Bt^T)[b][o] - x_sq[b] - psb[o]
// 64x64 tile, BK=64, 256 threads (4 waves 2x2, each 32x32 = 2x2 MFMA).
// 1024 blocks -> 4 blocks/CU, 4 waves/SIMD: TLP hides the barrier drain
// (R2 lesson: 1 block/CU + source-level dbuf regressed; occupancy is the fix).
// LDS chunk layout XOR-swizzled on the GLOBAL side of global_load_lds
// (LDS side must stay lane-contiguous) -> conflict-free ds_read_b128.
// XCD swizzle: each group of 8 consecutive n-tiles pinned to one XCD (lid&7).
// --------------------------------------------------------------------------
extern "C" __global__ __launch_bounds__(256) void gemm_epi(
        const unsigned short* __restrict__ A,
        const unsigned short* __restrict__ Bt,
        const float* __restrict__ x_sq,
        const float* __restrict__ psb,
        float* __restrict__ out) {
    __shared__ __align__(16) unsigned short lA[64 * 64];  // 8 KB, row = 64 elems
    __shared__ __align__(16) unsigned short lB[64 * 64];  // 8 KB

    // block swizzle: 16 m-tiles x 64 n-tiles; XCD k owns n-tiles [8k, 8k+8)
    const int lid = blockIdx.x;          // 0..1023
    const int xcd = lid & 7;
    const int wi  = lid >> 3;            // 0..127
    const int nt  = xcd * 8 + (wi & 7);  // 0..63
    const int mt  = wi >> 3;             // 0..15
    const int m0 = mt * 64;
    const int n0 = nt * 64;

    const int t = threadIdx.x;
    // staging: slot t = (row t>>3, phys chunk t&7); global chunk = phys ^ (row&7)
    const int rA = t >> 3;               // 0..31 (second half: +32, same &7)
    const int gc = (t & 7) ^ (rA & 7);
    const unsigned short* gA0 = A  + (size_t)(m0 + rA) * IN_DIM + gc * 8;
    const unsigned short* gA1 = gA0 + (size_t)32 * IN_DIM;
    const unsigned short* gB0 = Bt + (size_t)(n0 + rA) * IN_DIM + gc * 8;
    const unsigned short* gB1 = gB0 + (size_t)32 * IN_DIM;
    unsigned short* lA0 = lA + t * 8;
    unsigned short* lA1 = lA0 + 2048;
    unsigned short* lB0 = lB + t * 8;
    unsigned short* lB1 = lB0 + 2048;

    const int wave = t >> 6;
    const int lane = t & 63;
    const int wm = (wave & 1) * 32;
    const int wn = (wave >> 1) * 32;
    const int ln = lane & 15;
    const int qd = lane >> 4;
    const int sw = ln & 7;               // row&7 for all frag rows (wm,16i mult of 8)

    f32x4 acc[2][2] = {};

    for (int k0 = 0; k0 < IN_DIM; k0 += 64) {
        async16(gA0, lA0); async16(gA1, lA1);
        async16(gB0, lB0); async16(gB1, lB1);
        gA0 += 64; gA1 += 64; gB0 += 64; gB1 += 64;
        __syncthreads();   // drains vmcnt(0): tile visible

        bf16x8 af[2][2], bfr[2][2];
#pragma unroll
        for (int i = 0; i < 2; ++i)
#pragma unroll
            for (int kk = 0; kk < 2; ++kk) {
                const int pcA = (kk * 4 + qd) ^ sw;   // logical chunk ^ row&7
                af[i][kk]  = *(const bf16x8*)(lA + (wm + i * 16 + ln) * 64 + pcA * 8);
                bfr[i][kk] = *(const bf16x8*)(lB + (wn + i * 16 + ln) * 64 + pcA * 8);
            }
#pragma unroll
        for (int kk = 0; kk < 2; ++kk)
#pragma unroll
            for (int i = 0; i < 2; ++i)
#pragma unroll
                for (int j = 0; j < 2; ++j)
                    acc[i][j] = __builtin_amdgcn_mfma_f32_16x16x32_bf16(
                                    af[i][kk], bfr[j][kk], acc[i][j], 0, 0, 0);
        __syncthreads();   // all reads done before next stage overwrites
    }

    // epilogue: C/D layout col = lane&15, row = (lane>>4)*4 + reg
    const int rowb = m0 + wm;
    const int colb = n0 + wn;
#pragma unroll
    for (int j = 0; j < 2; ++j) {
        const int col = colb + j * 16 + ln;
        const float pb = psb[col];
#pragma unroll
        for (int i = 0; i < 2; ++i) {
            const int row0 = rowb + i * 16 + qd * 4;
#pragma unroll
            for (int rr = 0; rr < 4; ++rr) {
                const int row = row0 + rr;
                out[(size_t)row * OUT_DIM + col] = 2.0f * acc[i][j][rr] - x_sq[row] - pb;
            }
        }
    }
}

// --------------------------------------------------------------------------
extern "C" void kernel_launch(void* const* d_in, const int* in_sizes, int n_in,
                              void* d_out, int out_size, void* d_ws, size_t ws_size,
                              hipStream_t stream) {
    const float* x    = (const float*)d_in[0];   // [1024, 2048]
    const float* W    = (const float*)d_in[1];   // [4096, 2048]
    const float* bias = (const float*)d_in[2];   // [4096]
    float* out = (float*)d_out;

    char* ws = (char*)d_ws;
    unsigned short* protos = (unsigned short*)ws;                              // 16 MB
    unsigned short* xb     = (unsigned short*)(ws + (size_t)16 * 1024 * 1024); // 4 MB
    float* x_sq            = (float*)(ws + (size_t)20 * 1024 * 1024);          // 4 KB
    float* psb             = (float*)(ws + (size_t)20 * 1024 * 1024 + 8192);   // 16 KB

    transpose_w<<<dim3(32, 32, 2), 256, 0, stream>>>(W, protos);
    psq_bias<<<dim3(1024), 256, 0, stream>>>(protos, bias, psb);
    xcast_xsq<<<dim3(1024), 256, 0, stream>>>(x, xb, x_sq);
    gemm_epi<<<dim3(1024), 256, 0, stream>>>(xb, protos, x_sq, psb, out);
}

// Round 4
// 109.671 us; speedup vs baseline: 1.3252x; 1.0726x over previous
//
#include <hip/hip_runtime.h>

#define IN_DIM  2048
#define OUT_DIM 4096

typedef float     f32x4 __attribute__((ext_vector_type(4)));
typedef long long llx2  __attribute__((ext_vector_type(2)));

// pack 4 fp32 -> 4 fp8 e4m3 (RNE, HW)
__device__ __forceinline__ unsigned int pk4(float a, float b, float c, float d) {
    int v = __builtin_amdgcn_cvt_pk_fp8_f32(a, b, 0, false);   // bytes 0-1
    v     = __builtin_amdgcn_cvt_pk_fp8_f32(c, d, v, true);    // bytes 2-3
    return (unsigned int)v;
}

// async global->LDS, 16B/lane; LDS dest must be wave-uniform base + lane*16
__device__ __forceinline__ void async16(const void* g, void* l) {
    __builtin_amdgcn_global_load_lds(
        (const __attribute__((address_space(1))) unsigned int*)g,
        (__attribute__((address_space(3))) unsigned int*)l,
        16, 0, 0);
}

// k-interleaved fp8 row layout: within each 64B k-block, memory 8B-granule
// g holds logical k-chunk c(g) = (g>>1) + 4*(g&1); inverse g(c) = 2*(c&3)+(c>>2).
// => 16B position p holds chunks {p, p+4} = (kk=0,qd=p) and (kk=1,qd=p), so one
// ds_read_b128 yields BOTH K=32 fp8 fragments for quad qd.
__device__ __forceinline__ int gmem_of(int c) { return 2 * (c & 3) + (c >> 2); }

// --------------------------------------------------------------------------
// Kernel 1: W [4096][2048] fp32 -> protos fp8 [4096][2048] (x16 scale,
// k-interleaved layout), protos[2c+r][d] = 16*W[r*2048+d][c].
// Also accumulates psq[o] = sum_d W[...][c]^2 (EXACT fp32) via atomics.
// grid (32 c-tiles, 32 d-tiles, 2 halves) x 256 threads
// --------------------------------------------------------------------------
extern "C" __global__ __launch_bounds__(256) void transpose_w(
        const float* __restrict__ W, unsigned char* __restrict__ protos,
        float* __restrict__ psq) {
    __shared__ float tile[64][65];   // [d][c], +1 pad
    const int r  = blockIdx.z;
    const int c0 = blockIdx.x * 64;
    const int d0 = blockIdx.y * 64;
    const int t  = threadIdx.x;
    const int g  = t >> 4;
    const int cc = (t & 15) * 4;

    const float* Wp = W + (size_t)(r * IN_DIM + d0 + g) * IN_DIM + c0 + cc;
#pragma unroll
    for (int p = 0; p < 4; ++p) {
        const float4 v = *(const float4*)(Wp + (size_t)(16 * p) * IN_DIM);
        const int dl = g + 16 * p;
        tile[dl][cc]     = v.x;
        tile[dl][cc + 1] = v.y;
        tile[dl][cc + 2] = v.z;
        tile[dl][cc + 3] = v.w;
    }
    __syncthreads();

    const int c8 = t & 7;                 // k-chunk within the 64-d tile
    const int gm = gmem_of(c8);
#pragma unroll
    for (int p = 0; p < 2; ++p) {
        const int cr = (t >> 3) + 32 * p; // c-row 0..63
        float v[8];
        float ss = 0.f;
#pragma unroll
        for (int j = 0; j < 8; ++j) {     // banks: 8*c8 + (t>>3) -> 2-way, free
            v[j] = tile[8 * c8 + j][cr];
            ss += v[j] * v[j];
        }
        const int o = 2 * (c0 + cr) + r;
        uint2 pk;
        pk.x = pk4(16.f * v[0], 16.f * v[1], 16.f * v[2], 16.f * v[3]);
        pk.y = pk4(16.f * v[4], 16.f * v[5], 16.f * v[6], 16.f * v[7]);
        *(uint2*)(protos + (size_t)o * IN_DIM + d0 + gm * 8) = pk;
        // reduce ss over the 8 c8-lanes (t bits 0..2)
        ss += __shfl_xor(ss, 1);
        ss += __shfl_xor(ss, 2);
        ss += __shfl_xor(ss, 4);
        if (c8 == 0) atomicAdd(psq + o, ss);
    }
}

// --------------------------------------------------------------------------
// Kernel 2: x fp32 [1024][2048] -> xb fp8 (k-interleaved), x_sq fp32 exact
// --------------------------------------------------------------------------
extern "C" __global__ __launch_bounds__(256) void xcast_xsq(
        const float* __restrict__ x,
        unsigned char* __restrict__ xb,
        float* __restrict__ x_sq) {
    __shared__ float red[4];
    const int b = blockIdx.x;
    const int t = threadIdx.x;
    const float* xp = x + (size_t)b * IN_DIM + t * 8;
    const float4 v0 = ((const float4*)xp)[0];
    const float4 v1 = ((const float4*)xp)[1];
    uint2 pk;
    pk.x = pk4(v0.x, v0.y, v0.z, v0.w);
    pk.y = pk4(v1.x, v1.y, v1.z, v1.w);
    // t*8 elems = k-block t>>3, chunk t&7 -> interleaved granule position
    *(uint2*)(xb + (size_t)b * IN_DIM + (t >> 3) * 64 + gmem_of(t & 7) * 8) = pk;

    float s = v0.x * v0.x + v0.y * v0.y + v0.z * v0.z + v0.w * v0.w
            + v1.x * v1.x + v1.y * v1.y + v1.z * v1.z + v1.w * v1.w;
#pragma unroll
    for (int off = 32; off > 0; off >>= 1) s += __shfl_down(s, off);
    const int lane = t & 63, w = t >> 6;
    if (lane == 0) red[w] = s;
    __syncthreads();
    if (t == 0) x_sq[b] = red[0] + red[1] + red[2] + red[3];
}

// --------------------------------------------------------------------------
// Kernel 3: fp8 GEMM + epilogue.
// out[b][o] = 0.125*acc - x_sq[b] - (psq[o] + bias[o]),  acc = (x_fp8)·(16*W)_fp8
// 64x64 tile, BK=64, 256 thr (4 waves 2x2, each 32x32 = 2x2 MFMA 16x16x32 fp8).
// 1024 blocks = 4 blocks/CU = 4 waves/SIMD (R2/R3 lesson: TLP is the latency fix).
// One ds_read_b128 per row-pair = 2 fragments (k-interleaved layout) -> LDS
// read traffic is 1/4 of the bf16-R3 kernel; staging bytes halved.
// 16B-granule XOR swizzle (pos ^ ((row>>1)&3)) on the GLOBAL side of
// global_load_lds -> frag-read start banks hit each 4-aligned bank twice: free.
// --------------------------------------------------------------------------
extern "C" __global__ __launch_bounds__(256) void gemm_epi(
        const unsigned char* __restrict__ A,
        const unsigned char* __restrict__ Bt,
        const float* __restrict__ x_sq,
        const float* __restrict__ psq,
        const float* __restrict__ bias,
        float* __restrict__ out) {
    __shared__ __align__(16) unsigned char lA[64 * 64];  // 4 KB (row = 64 B)
    __shared__ __align__(16) unsigned char lB[64 * 64];  // 4 KB

    const int lid = blockIdx.x;          // XCD swizzle: XCD k owns n-tiles [8k,8k+8)
    const int xcd = lid & 7;
    const int wi  = lid >> 3;
    const int nt  = xcd * 8 + (wi & 7);
    const int mt  = wi >> 3;
    const int m0 = mt * 64;
    const int n0 = nt * 64;

    const int t  = threadIdx.x;
    const int rS = t >> 2;               // staged row 0..63
    const int pS = (t & 3) ^ ((rS >> 1) & 3);   // logical 16B pos for this slot
    const unsigned char* gA = A  + (size_t)(m0 + rS) * IN_DIM + pS * 16;
    const unsigned char* gB = Bt + (size_t)(n0 + rS) * IN_DIM + pS * 16;
    unsigned char* lAd = lA + t * 16;
    unsigned char* lBd = lB + t * 16;

    const int wave = t >> 6;
    const int lane = t & 63;
    const int wm = (wave & 1) * 32;
    const int wn = (wave >> 1) * 32;
    const int ln = lane & 15;
    const int qd = lane >> 4;
    const int pf = qd ^ ((ln >> 1) & 3); // phys 16B pos for frag reads

    f32x4 acc[2][2] = {};

    for (int k0 = 0; k0 < IN_DIM; k0 += 64) {
        async16(gA, lAd);
        async16(gB, lBd);
        gA += 64; gB += 64;
        __syncthreads();   // vmcnt drain: tile visible

        llx2 af[2], bf[2];
#pragma unroll
        for (int i = 0; i < 2; ++i)
            af[i] = *(const llx2*)(lA + (wm + i * 16 + ln) * 64 + pf * 16);
#pragma unroll
        for (int j = 0; j < 2; ++j)
            bf[j] = *(const llx2*)(lB + (wn + j * 16 + ln) * 64 + pf * 16);
#pragma unroll
        for (int kk = 0; kk < 2; ++kk)
#pragma unroll
            for (int i = 0; i < 2; ++i)
#pragma unroll
                for (int j = 0; j < 2; ++j)
                    acc[i][j] = __builtin_amdgcn_mfma_f32_16x16x32_fp8_fp8(
                                    af[i][kk], bf[j][kk], acc[i][j], 0, 0, 0);
        __syncthreads();   // reads done before next stage overwrites
    }

    // epilogue: C/D layout col = lane&15, row = (lane>>4)*4 + reg
    const int rowb = m0 + wm;
    const int colb = n0 + wn;
#pragma unroll
    for (int j = 0; j < 2; ++j) {
        const int col = colb + j * 16 + ln;
        const float pb = psq[col] + bias[col];
#pragma unroll
        for (int i = 0; i < 2; ++i) {
            const int row0 = rowb + i * 16 + qd * 4;
#pragma unroll
            for (int rr = 0; rr < 4; ++rr) {
                const int row = row0 + rr;
                out[(size_t)row * OUT_DIM + col] =
                    0.125f * acc[i][j][rr] - x_sq[row] - pb;
            }
        }
    }
}

// --------------------------------------------------------------------------
extern "C" void kernel_launch(void* const* d_in, const int* in_sizes, int n_in,
                              void* d_out, int out_size, void* d_ws, size_t ws_size,
                              hipStream_t stream) {
    const float* x    = (const float*)d_in[0];   // [1024, 2048]
    const float* W    = (const float*)d_in[1];   // [4096, 2048]
    const float* bias = (const float*)d_in[2];   // [4096]
    float* out = (float*)d_out;

    char* ws = (char*)d_ws;
    unsigned char* protos = (unsigned char*)ws;                               // 8 MB
    unsigned char* xb     = (unsigned char*)(ws + (size_t)8 * 1024 * 1024);   // 2 MB
    float* x_sq           = (float*)(ws + (size_t)10 * 1024 * 1024);          // 4 KB
    float* psq            = (float*)(ws + (size_t)10 * 1024 * 1024 + 8192);   // 16 KB

    hipMemsetAsync(psq, 0, OUT_DIM * sizeof(float), stream);
    transpose_w<<<dim3(32, 32, 2), 256, 0, stream>>>(W, protos, psq);
    xcast_xsq<<<dim3(1024), 256, 0, stream>>>(x, xb, x_sq);
    gemm_epi<<<dim3(1024), 256, 0, stream>>>(xb, protos, x_sq, psq, bias, out);
}

// Round 5
// 109.056 us; speedup vs baseline: 1.3327x; 1.0056x over previous
//
#include <hip/hip_runtime.h>

#define IN_DIM  2048
#define OUT_DIM 4096

typedef float     f32x4 __attribute__((ext_vector_type(4)));
typedef long long llx2  __attribute__((ext_vector_type(2)));

// pack 4 fp32 -> 4 fp8 e4m3 (RNE, HW)
__device__ __forceinline__ unsigned int pk4(float a, float b, float c, float d) {
    int v = __builtin_amdgcn_cvt_pk_fp8_f32(a, b, 0, false);   // bytes 0-1
    v     = __builtin_amdgcn_cvt_pk_fp8_f32(c, d, v, true);    // bytes 2-3
    return (unsigned int)v;
}

// async global->LDS, 16B/lane; LDS dest must be wave-uniform base + lane*16
__device__ __forceinline__ void async16(const void* g, void* l) {
    __builtin_amdgcn_global_load_lds(
        (const __attribute__((address_space(1))) unsigned int*)g,
        (__attribute__((address_space(3))) unsigned int*)l,
        16, 0, 0);
}

// k-interleaved fp8 row layout: within each 64B-aligned k-block, memory
// 8B-granule g holds logical k-chunk c(g) = (g>>1) + 4*(g&1); inverse
// g(c) = 2*(c&3)+(c>>2).  => 16B position p holds chunks {p, p+4}, i.e. the
// (kk=0,qd=p) and (kk=1,qd=p) fragments: one ds_read_b128 = 2 fp8 fragments.
__device__ __forceinline__ int gmem_of(int c) { return 2 * (c & 3) + (c >> 2); }

// --------------------------------------------------------------------------
// Kernel 1 (launched 2nd): W [4096][2048] fp32 -> protos fp8 (x16 scale,
// k-interleaved), protos[2c+r][d] = 16*W[r*2048+d][c]; psq[o] += exact
// fp32 row-sumsq via atomics (psq zeroed by xcast_xsq, which runs first).
// --------------------------------------------------------------------------
extern "C" __global__ __launch_bounds__(256) void transpose_w(
        const float* __restrict__ W, unsigned char* __restrict__ protos,
        float* __restrict__ psq) {
    __shared__ float tile[64][65];   // [d][c], +1 pad
    const int r  = blockIdx.z;
    const int c0 = blockIdx.x * 64;
    const int d0 = blockIdx.y * 64;
    const int t  = threadIdx.x;
    const int g  = t >> 4;
    const int cc = (t & 15) * 4;

    const float* Wp = W + (size_t)(r * IN_DIM + d0 + g) * IN_DIM + c0 + cc;
#pragma unroll
    for (int p = 0; p < 4; ++p) {
        const float4 v = *(const float4*)(Wp + (size_t)(16 * p) * IN_DIM);
        const int dl = g + 16 * p;
        tile[dl][cc]     = v.x;
        tile[dl][cc + 1] = v.y;
        tile[dl][cc + 2] = v.z;
        tile[dl][cc + 3] = v.w;
    }
    __syncthreads();

    const int c8 = t & 7;                 // k-chunk within the 64-d tile
    const int gm = gmem_of(c8);
#pragma unroll
    for (int p = 0; p < 2; ++p) {
        const int cr = (t >> 3) + 32 * p; // c-row 0..63
        float v[8];
        float ss = 0.f;
#pragma unroll
        for (int j = 0; j < 8; ++j) {
            v[j] = tile[8 * c8 + j][cr];
            ss += v[j] * v[j];
        }
        const int o = 2 * (c0 + cr) + r;
        uint2 pk;
        pk.x = pk4(16.f * v[0], 16.f * v[1], 16.f * v[2], 16.f * v[3]);
        pk.y = pk4(16.f * v[4], 16.f * v[5], 16.f * v[6], 16.f * v[7]);
        *(uint2*)(protos + (size_t)o * IN_DIM + d0 + gm * 8) = pk;
        ss += __shfl_xor(ss, 1);
        ss += __shfl_xor(ss, 2);
        ss += __shfl_xor(ss, 4);
        if (c8 == 0) atomicAdd(psq + o, ss);
    }
}

// --------------------------------------------------------------------------
// Kernel 2 (launched FIRST): x -> xb fp8 (k-interleaved), x_sq exact fp32,
// and zeroes psq (replaces the hipMemsetAsync dispatch; stream order makes
// this safe w.r.t. transpose_w's atomics).
// --------------------------------------------------------------------------
extern "C" __global__ __launch_bounds__(256) void xcast_xsq(
        const float* __restrict__ x,
        unsigned char* __restrict__ xb,
        float* __restrict__ x_sq,
        float* __restrict__ psq) {
    __shared__ float red[4];
    const int b = blockIdx.x;
    const int t = threadIdx.x;
    if (t < 4) psq[b * 4 + t] = 0.f;
    const float* xp = x + (size_t)b * IN_DIM + t * 8;
    const float4 v0 = ((const float4*)xp)[0];
    const float4 v1 = ((const float4*)xp)[1];
    uint2 pk;
    pk.x = pk4(v0.x, v0.y, v0.z, v0.w);
    pk.y = pk4(v1.x, v1.y, v1.z, v1.w);
    *(uint2*)(xb + (size_t)b * IN_DIM + (t >> 3) * 64 + gmem_of(t & 7) * 8) = pk;

    float s = v0.x * v0.x + v0.y * v0.y + v0.z * v0.z + v0.w * v0.w
            + v1.x * v1.x + v1.y * v1.y + v1.z * v1.z + v1.w * v1.w;
#pragma unroll
    for (int off = 32; off > 0; off >>= 1) s += __shfl_down(s, off);
    const int lane = t & 63, w = t >> 6;
    if (lane == 0) red[w] = s;
    __syncthreads();
    if (t == 0) x_sq[b] = red[0] + red[1] + red[2] + red[3];
}

// --------------------------------------------------------------------------
// Kernel 3: fp8 GEMM + epilogue, K-SPLIT wave decomposition.
// Block = 64M x 64N, 1024 blocks (4/CU, 4 waves/SIMD). Wave w: kh=w&1 owns
// K-half [kh*1024,+1024), nh=w>>1 owns N cols [nh*32,+32). Wave tile
// 64Mx32N = 4x2 acc -> frag reads 6 b128 per 16 MFMA (was 4 per 8): -25%
// LDS read instrs vs R4. kh partial sums reduced through 16 KB LDS at end.
// LDS row = 128B (2 k-halves x 64B, each 64B block k-interleaved); frag/
// staging position swizzle p = l ^ (row&7) -> pure 2-way reads (free, m136).
// --------------------------------------------------------------------------
extern "C" __global__ __launch_bounds__(256, 4) void gemm_epi(
        const unsigned char* __restrict__ A,
        const unsigned char* __restrict__ Bt,
        const float* __restrict__ x_sq,
        const float* __restrict__ psq,
        const float* __restrict__ bias,
        float* __restrict__ out) {
    __shared__ __align__(16) unsigned char smem[16384];
    unsigned char* lA = smem;           // 8 KB: 64 rows x 128 B
    unsigned char* lB = smem + 8192;    // 8 KB

    const int lid = blockIdx.x;          // XCD swizzle: XCD k owns n-tiles [8k,8k+8)
    const int xcd = lid & 7;
    const int wi  = lid >> 3;
    const int nt  = xcd * 8 + (wi & 7);
    const int mt  = wi >> 3;
    const int m0 = mt * 64;
    const int n0 = nt * 64;

    const int t = threadIdx.x;
    // staging: thread t owns LDS bytes [16t,16t+16) and [4096+16t, +16) of
    // each of lA/lB. off -> row=off>>7, phys pos p=(off>>4)&7; logical
    // l = p ^ (row&7); l -> k-half l>>2, 16B-chunk l&3 of the 64B block.
    const int rS = t >> 3;               // row 0..31 (2nd chunk: +32, same &7)
    const int pS = t & 7;
    const int lS = pS ^ (rS & 7);
    const size_t goff = (size_t)(lS >> 2) * 1024 + (lS & 3) * 16;
    const unsigned char* gA0 = A  + (size_t)(m0 + rS) * IN_DIM + goff;
    const unsigned char* gA1 = gA0 + (size_t)32 * IN_DIM;
    const unsigned char* gB0 = Bt + (size_t)(n0 + rS) * IN_DIM + goff;
    const unsigned char* gB1 = gB0 + (size_t)32 * IN_DIM;
    unsigned char* lAd = lA + t * 16;
    unsigned char* lBd = lB + t * 16;

    const int wave = t >> 6;
    const int lane = t & 63;
    const int kh = wave & 1;             // K-half this wave owns
    const int nh = wave >> 1;            // N-half this wave owns
    const int ln = lane & 15;
    const int qd = lane >> 4;
    const int pr = (kh * 4 + qd) ^ (ln & 7);   // phys 16B pos for frag reads

    f32x4 acc[4][2] = {};

    for (int it = 0; it < 16; ++it) {    // BK=64 per half per iter
        async16(gA0, lAd); async16(gA1, lAd + 4096);
        async16(gB0, lBd); async16(gB1, lBd + 4096);
        gA0 += 64; gA1 += 64; gB0 += 64; gB1 += 64;
        __syncthreads();                 // vmcnt drain: tile visible

        llx2 af[4], bf[2];
#pragma unroll
        for (int i = 0; i < 4; ++i)
            af[i] = *(const llx2*)(lA + (i * 16 + ln) * 128 + pr * 16);
#pragma unroll
        for (int j = 0; j < 2; ++j)
            bf[j] = *(const llx2*)(lB + (nh * 32 + j * 16 + ln) * 128 + pr * 16);
#pragma unroll
        for (int kk = 0; kk < 2; ++kk)
#pragma unroll
            for (int i = 0; i < 4; ++i)
#pragma unroll
                for (int j = 0; j < 2; ++j)
                    acc[i][j] = __builtin_amdgcn_mfma_f32_16x16x32_fp8_fp8(
                                    af[i][kk], bf[j][kk], acc[i][j], 0, 0, 0);
        __syncthreads();                 // reads done before next stage
    }

    // cross-K-half reduction: kh=1 waves dump acc to LDS, kh=0 waves add.
    if (kh == 1) {
#pragma unroll
        for (int i = 0; i < 4; ++i)
#pragma unroll
            for (int j = 0; j < 2; ++j)
                *(f32x4*)(smem + nh * 8192 + (i * 2 + j) * 1024 + lane * 16) =
                    acc[i][j];
    }
    __syncthreads();
    if (kh == 0) {
        const int rowb = m0;
        const int colb = n0 + nh * 32;
#pragma unroll
        for (int j = 0; j < 2; ++j) {
            const int col = colb + j * 16 + ln;
            const float pb = psq[col] + bias[col];
#pragma unroll
            for (int i = 0; i < 4; ++i) {
                const f32x4 o4 = *(const f32x4*)(smem + nh * 8192 +
                                                 (i * 2 + j) * 1024 + lane * 16);
                const int row0 = rowb + i * 16 + qd * 4;
#pragma unroll
                for (int rr = 0; rr < 4; ++rr) {
                    const int row = row0 + rr;
                    out[(size_t)row * OUT_DIM + col] =
                        0.125f * (acc[i][j][rr] + o4[rr]) - x_sq[row] - pb;
                }
            }
        }
    }
}

// --------------------------------------------------------------------------
extern "C" void kernel_launch(void* const* d_in, const int* in_sizes, int n_in,
                              void* d_out, int out_size, void* d_ws, size_t ws_size,
                              hipStream_t stream) {
    const float* x    = (const float*)d_in[0];   // [1024, 2048]
    const float* W    = (const float*)d_in[1];   // [4096, 2048]
    const float* bias = (const float*)d_in[2];   // [4096]
    float* out = (float*)d_out;

    char* ws = (char*)d_ws;
    unsigned char* protos = (unsigned char*)ws;                               // 8 MB
    unsigned char* xb     = (unsigned char*)(ws + (size_t)8 * 1024 * 1024);   // 2 MB
    float* x_sq           = (float*)(ws + (size_t)10 * 1024 * 1024);          // 4 KB
    float* psq            = (float*)(ws + (size_t)10 * 1024 * 1024 + 8192);   // 16 KB

    xcast_xsq<<<dim3(1024), 256, 0, stream>>>(x, xb, x_sq, psq);   // zeroes psq
    transpose_w<<<dim3(32, 32, 2), 256, 0, stream>>>(W, protos, psq);
    gemm_epi<<<dim3(1024), 256, 0, stream>>>(xb, protos, x_sq, psq, bias, out);
}